// Round 5
// baseline (1418.495 us; speedup 1.0000x reference)
//
#include <hip/hip_runtime.h>
#include <math.h>

#define NPTS 65536
#define DIMD 256
#define KCB  4096
#define MARGIN 2.0f

// d_out float32 offsets (reference tuple order, flattened)
#define O_ZQ   0
#define O_IDX  16777216
#define O_LOSS 16842752
#define O_PERP 16842753
#define O_CS   16842754
#define O_EMAW 16846850
#define O_W    17895426

// scratch inside d_out O_ZQ region (16,777,216 floats; dead until k_zq):
#define OFF_WBF   8388608      // 4096 x 128 uints
#define OFF_CAND  8912896      // 65536 x 17 ints
#define OFF_OFFS  10027008     // 4097 ints
#define OFF_CUR   10031232     // 4096 ints
#define OFF_ROWS  10035328     // 65536 ints
// zz -> EMAW region [0,65536); wwg -> EMAW [65536,69632)  (dead before k_dw)

typedef __attribute__((address_space(3))) void lds_void;
typedef const __attribute__((address_space(1))) void gbl_void;
typedef __attribute__((ext_vector_type(8))) short short8;   // 8 bf16
typedef __attribute__((ext_vector_type(4))) float f32x4;

__device__ __forceinline__ void dma16(const void* g, void* l) {
    __builtin_amdgcn_global_load_lds((gbl_void*)g, (lds_void*)l, 16, 0, 0);
}
__device__ __forceinline__ unsigned short f2bf(float f) {   // RNE
    unsigned u = __float_as_uint(f);
    return (unsigned short)((u + 0x7FFF + ((u >> 16) & 1)) >> 16);
}

// ---------------- fp32 -> bf16 pack + row sum-of-squares ----------------
__global__ void k_prep(const float* __restrict__ src, unsigned* __restrict__ dst,
                       float* __restrict__ ss) {
    int l   = threadIdx.x & 63;
    int row = blockIdx.x * 4 + (threadIdx.x >> 6);
    float4 v = ((const float4*)(src + (size_t)row * DIMD))[l];
    unsigned b0 = f2bf(v.x), b1 = f2bf(v.y), b2 = f2bf(v.z), b3 = f2bf(v.w);
    uint2 pk = make_uint2(b0 | (b1 << 16), b2 | (b3 << 16));
    ((uint2*)dst)[(size_t)row * 64 + l] = pk;
    float s = v.x*v.x + v.y*v.y + v.z*v.z + v.w*v.w;
    #pragma unroll
    for (int off = 32; off; off >>= 1) s += __shfl_down(s, off);
    if (l == 0) ss[row] = s;
}

// ---------------- coarse bf16 MFMA argmin, 2-sweep + margin lists ----------
// 512 blocks x 128 thr (2 waves x 64 rows). k-tiles of 64 codes, double-buffered
// DMA staging. Each wave holds 4 A-frag sets (64 rows); one B ds_read feeds 4
// MFMAs. LDS 74 KB -> 2 blocks/CU.
__launch_bounds__(128)
__global__ void k_coarse(const unsigned* __restrict__ zbf,   // [N][256] bf16
                         const unsigned* __restrict__ wbf,   // [K][256] bf16
                         const float* __restrict__ wwg,
                         int* __restrict__ cand) {           // [N][17]
    __shared__ uint4 wtile[2][2048];       // 2 x 32 KB
    __shared__ int   cnt[128];
    __shared__ int   ids[128][16];

    const int t    = threadIdx.x;          // 0..127
    const int wv   = t >> 6;
    const int l    = t & 63;
    const int q    = l >> 4;
    const int n16  = l & 15;
    const int row0 = blockIdx.x * 128;
    const char* wb = (const char*)wbf;

    union U { uint4 u; short8 s; };
    U afr[4][8];                           // 4 sets x 8 chunks (128 VGPR)
    #pragma unroll
    for (int s = 0; s < 4; ++s) {
        int row = row0 + wv * 64 + s * 16 + n16;
        const char* zb = (const char*)zbf + ((size_t)row << 9) + q * 16;
        #pragma unroll
        for (int c = 0; c < 8; ++c)
            afr[s][c].u = *(const uint4*)(zb + c * 64);
    }

    float minv[16], gmin[16];
    #pragma unroll
    for (int i = 0; i < 16; ++i) minv[i] = 3.0e38f;

    for (int pass = 0; pass < 2; ++pass) {
        if (pass == 1) cnt[t] = 0;
        // stage tile 0 -> buf 0 (16 rounds x 2 KB)
        #pragma unroll
        for (int r = 0; r < 16; ++r) {
            int f0 = r * 128 + wv * 64;
            int st = f0 >> 9, c = (f0 >> 6) & 7;
            const char* g = wb + ((size_t)(st * 16 + n16) << 9) + c * 64 + q * 16;
            dma16(g, (char*)&wtile[0][f0]);
        }
        __syncthreads();

        for (int kt = 0; kt < KCB / 64; ++kt) {
            const int k0  = kt * 64;
            const int cur = kt & 1;
            if (kt + 1 < KCB / 64) {       // prefetch next tile
                #pragma unroll
                for (int r = 0; r < 16; ++r) {
                    int f0 = r * 128 + wv * 64;
                    int st = f0 >> 9, c = (f0 >> 6) & 7;
                    const char* g = wb + ((size_t)(k0 + 64 + st * 16 + n16) << 9)
                                  + c * 64 + q * 16;
                    dma16(g, (char*)&wtile[cur ^ 1][f0]);
                }
            }
            #pragma unroll
            for (int st = 0; st < 4; ++st) {
                f32x4 acc[4];
                #pragma unroll
                for (int s = 0; s < 4; ++s) acc[s] = (f32x4){0.f, 0.f, 0.f, 0.f};
                const uint4* wt = &wtile[cur][st * 512];
                #pragma unroll
                for (int c = 0; c < 8; ++c) {
                    U bf; bf.u = wt[c * 64 + l];
                    #pragma unroll
                    for (int s = 0; s < 4; ++s)
                        acc[s] = __builtin_amdgcn_mfma_f32_16x16x32_bf16(
                                     afr[s][c].s, bf.s, acc[s], 0, 0, 0);
                }
                float wwv = wwg[k0 + st * 16 + n16];
                if (pass == 0) {
                    #pragma unroll
                    for (int s = 0; s < 4; ++s)
                        #pragma unroll
                        for (int r = 0; r < 4; ++r)
                            minv[s * 4 + r] = fminf(minv[s * 4 + r],
                                                    fmaf(-2.f, acc[s][r], wwv));
                } else {
                    #pragma unroll
                    for (int s = 0; s < 4; ++s)
                        #pragma unroll
                        for (int r = 0; r < 4; ++r) {
                            float core = fmaf(-2.f, acc[s][r], wwv);
                            if (core <= gmin[s * 4 + r] + MARGIN) {
                                int row_l = wv * 64 + s * 16 + q * 4 + r;
                                int pos = atomicAdd(&cnt[row_l], 1);
                                if (pos < 16) ids[row_l][pos] = k0 + st * 16 + n16;
                            }
                        }
                }
            }
            __syncthreads();
        }
        if (pass == 0) {   // butterfly min over the 16 n16-lanes
            #pragma unroll
            for (int i = 0; i < 16; ++i) {
                float m = minv[i];
                #pragma unroll
                for (int msk = 1; msk < 16; msk <<= 1)
                    m = fminf(m, __shfl_xor(m, msk));
                gmin[i] = m;
            }
        }
    }
    // flush lists (t indexes the block's 128 rows)
    int n = cnt[t]; if (n > 16) n = 16;
    int* dst = cand + (size_t)(row0 + t) * 17;
    dst[0] = n;
    for (int j = 0; j < n; ++j) dst[1 + j] = ids[t][j];
}

// ---------------- fp32 rescore of candidates ----------------
__global__ void k_refine(const float* __restrict__ z,
                         const float* __restrict__ w,
                         const float* __restrict__ zz,
                         const float* __restrict__ wwg,
                         const int* __restrict__ cand,
                         float* __restrict__ counts,
                         int*   __restrict__ idxi,
                         float* __restrict__ idxf) {
    int l   = threadIdx.x & 63;
    int row = blockIdx.x * 4 + (threadIdx.x >> 6);
    const int* cl = cand + (size_t)row * 17;
    int n = cl[0];
    float4 zv = ((const float4*)(z + (size_t)row * DIMD))[l];
    float zzv = zz[row];
    float bd = 3.0e38f; int bi = 0x7fffffff;
    for (int j = 0; j < n; ++j) {
        int k = cl[1 + j];
        float4 wv = ((const float4*)(w + (size_t)k * DIMD))[l];
        float s = zv.x*wv.x + zv.y*wv.y + zv.z*wv.z + zv.w*wv.w;
        #pragma unroll
        for (int off = 32; off; off >>= 1) s += __shfl_xor(s, off);
        float d = (zzv + wwg[k]) - 2.0f * s;
        if (d < bd || (d == bd && k < bi)) { bd = d; bi = k; }
    }
    if (l == 0) {
        idxi[row] = bi;
        idxf[row] = (float)bi;
        atomicAdd(&counts[bi], 1.0f);
    }
}

// ---------------- exclusive prefix sum of counts -> offs, cursor ----------
__global__ void k_offsets(const float* __restrict__ counts,
                          int* __restrict__ offs, int* __restrict__ cursor) {
    __shared__ int sc[1024];
    int t = threadIdx.x;
    int c[4]; int s = 0;
    #pragma unroll
    for (int i = 0; i < 4; ++i) { c[i] = (int)counts[t * 4 + i]; s += c[i]; }
    sc[t] = s;
    __syncthreads();
    for (int d = 1; d < 1024; d <<= 1) {
        int v = (t >= d) ? sc[t - d] : 0;
        __syncthreads();
        sc[t] += v;
        __syncthreads();
    }
    int o = sc[t] - s;
    #pragma unroll
    for (int i = 0; i < 4; ++i) { offs[t*4+i] = o; cursor[t*4+i] = o; o += c[i]; }
    if (t == 1023) offs[4096] = sc[1023];
}

// ---------------- fill inverted row lists ----------------
__global__ void k_fill(const int* __restrict__ idxi, int* __restrict__ cursor,
                       int* __restrict__ rows) {
    int r = blockIdx.x * 256 + threadIdx.x;
    int k = idxi[r];
    int pos = atomicAdd(&cursor[k], 1);
    rows[pos] = r;
}

// ---------------- dw[k,:] = sum of z rows assigned to k (no atomics) ------
__global__ void k_dw(const float* __restrict__ z, const int* __restrict__ offs,
                     const int* __restrict__ rows, float* __restrict__ dw) {
    int k = blockIdx.x, l = threadIdx.x;   // 64 threads
    int o0 = offs[k], o1 = offs[k + 1];
    float4 a = make_float4(0.f, 0.f, 0.f, 0.f);
    for (int i = o0; i < o1; ++i) {
        int r = rows[i];
        float4 v = ((const float4*)(z + (size_t)r * DIMD))[l];
        a.x += v.x; a.y += v.y; a.z += v.z; a.w += v.w;
    }
    ((float4*)(dw + (size_t)k * DIMD))[l] = a;
}

// ---------------- cluster-size EMA + perplexity ----------------
__global__ void k_cs(const float* __restrict__ ema_cs,
                     float* __restrict__ cs_io,
                     float* __restrict__ perp) {
    __shared__ float2 red[16];
    int t = threadIdx.x;
    float csd[4];
    float nl = 0.f, el = 0.f;
    #pragma unroll
    for (int i = 0; i < 4; ++i) {
        int k = t * 4 + i;
        float c  = cs_io[k];
        float cd = ema_cs[k] * 0.99f + 0.01f * c;
        csd[i] = cd;
        nl += cd;
        float p = c * (1.0f / 65536.0f);
        el += p * logf(p + 1e-10f);
    }
    #pragma unroll
    for (int off = 32; off; off >>= 1) { nl += __shfl_down(nl, off); el += __shfl_down(el, off); }
    if ((t & 63) == 0) red[t >> 6] = make_float2(nl, el);
    __syncthreads();
    if (t == 0) {
        float n = 0.f, e = 0.f;
        for (int i = 0; i < 16; ++i) { n += red[i].x; e += red[i].y; }
        red[0] = make_float2(n, e);
        perp[0] = expf(-e);
    }
    __syncthreads();
    float n = red[0].x;
    float scale = n / (n + 4096.0f * 1e-5f);
    #pragma unroll
    for (int i = 0; i < 4; ++i)
        cs_io[t * 4 + i] = (csd[i] + 1e-5f) * scale;
}

// ---------------- new_ema_w (in-place over dw) + new_weight ----------------
__global__ void k_emaw(const float* __restrict__ ema_w,
                       const float* __restrict__ cs,
                       float* __restrict__ emaw_io,
                       float* __restrict__ wout) {
    int i = (blockIdx.x * 256 + threadIdx.x) * 4;
    int k = i >> 8;
    float4 dv = *(const float4*)(emaw_io + i);
    float4 ev = *(const float4*)(ema_w + i);
    float c = cs[k];
    float4 ne;
    ne.x = ev.x * 0.99f + 0.01f * dv.x;
    ne.y = ev.y * 0.99f + 0.01f * dv.y;
    ne.z = ev.z * 0.99f + 0.01f * dv.z;
    ne.w = ev.w * 0.99f + 0.01f * dv.w;
    *(float4*)(emaw_io + i) = ne;
    float4 nw = make_float4(ne.x / c, ne.y / c, ne.z / c, ne.w / c);
    *(float4*)(wout + i) = nw;
}

// ---------------- z_q gather + straight-through + loss partial ----------------
__global__ void k_zq(const float* __restrict__ z,
                     const float* __restrict__ wnew,
                     const int* __restrict__ idxi,
                     float* __restrict__ zq,
                     float* __restrict__ sqacc) {
    __shared__ float red[4];
    int i = (blockIdx.x * 256 + threadIdx.x) * 4;
    int n = i >> 8;
    int d = i & 255;
    int k = idxi[n];
    float4 wv = *(const float4*)(wnew + (k << 8) + d);
    float4 zv = *(const float4*)(z + i);
    float4 o;
    o.x = zv.x + (wv.x - zv.x);
    o.y = zv.y + (wv.y - zv.y);
    o.z = zv.z + (wv.z - zv.z);
    o.w = zv.w + (wv.w - zv.w);
    *(float4*)(zq + i) = o;
    float dx = wv.x - zv.x, dy = wv.y - zv.y, dz = wv.z - zv.z, dw_ = wv.w - zv.w;
    float s = dx*dx + dy*dy + dz*dz + dw_*dw_;
    #pragma unroll
    for (int off = 32; off; off >>= 1) s += __shfl_down(s, off);
    int lane = threadIdx.x & 63;
    if (lane == 0) red[threadIdx.x >> 6] = s;
    __syncthreads();
    if (threadIdx.x == 0) atomicAdd(sqacc, red[0] + red[1] + red[2] + red[3]);
}

__global__ void k_final(const float* __restrict__ sqacc, float* __restrict__ loss) {
    loss[0] = 1.25f * sqacc[0] * (1.0f / 16777216.0f);
}

extern "C" void kernel_launch(void* const* d_in, const int* in_sizes, int n_in,
                              void* d_out, int out_size, void* d_ws, size_t ws_size,
                              hipStream_t stream) {
    const float* z      = (const float*)d_in[0];
    const float* weight = (const float*)d_in[1];
    const float* ema_w  = (const float*)d_in[2];
    const float* ema_cs = (const float*)d_in[3];
    float* out = (float*)d_out;
    float* ws  = (float*)d_ws;

    float* scal = ws + 4096;             // 16 floats
    int*   idxi = (int*)(ws + 8192);     // 65536 ints

    unsigned* zbf    = (unsigned*)(out + O_ZQ);
    unsigned* wbf    = (unsigned*)(out + O_ZQ + OFF_WBF);
    int*      cand   = (int*)(out + O_ZQ + OFF_CAND);
    int*      offs   = (int*)(out + O_ZQ + OFF_OFFS);
    int*      cursor = (int*)(out + O_ZQ + OFF_CUR);
    int*      rows   = (int*)(out + O_ZQ + OFF_ROWS);
    float*    zz     = out + O_EMAW;             // dead before k_dw writes dw
    float*    wwg    = out + O_EMAW + 65536;

    hipMemsetAsync(scal,       0, 16 * 4, stream);
    hipMemsetAsync(out + O_CS, 0, (size_t)KCB * 4, stream);

    k_prep   <<<NPTS / 4, 256, 0, stream>>>(z, zbf, zz);
    k_prep   <<<KCB  / 4, 256, 0, stream>>>(weight, wbf, wwg);
    k_coarse <<<NPTS / 128, 128, 0, stream>>>(zbf, wbf, wwg, cand);
    k_refine <<<NPTS / 4, 256, 0, stream>>>(z, weight, zz, wwg, cand,
                                            out + O_CS, idxi, out + O_IDX);
    k_offsets<<<1, 1024, 0, stream>>>(out + O_CS, offs, cursor);
    k_fill   <<<NPTS / 256, 256, 0, stream>>>(idxi, cursor, rows);
    k_cs     <<<1, 1024, 0, stream>>>(ema_cs, out + O_CS, out + O_PERP);
    k_dw     <<<KCB, 64, 0, stream>>>(z, offs, rows, out + O_EMAW);
    k_emaw   <<<(KCB * DIMD) / 1024, 256, 0, stream>>>(ema_w, out + O_CS,
                                                       out + O_EMAW, out + O_W);
    k_zq     <<<(NPTS * DIMD) / 1024, 256, 0, stream>>>(z, out + O_W, idxi,
                                                        out + O_ZQ, scal);
    k_final  <<<1, 1, 0, stream>>>(scal, out + O_LOSS);
}

// Round 6
// 788.549 us; speedup vs baseline: 1.7989x; 1.7989x over previous
//
#include <hip/hip_runtime.h>
#include <math.h>

#define NPTS 65536
#define DIMD 256
#define KCB  4096
#define MARGIN 2.0f

// d_out float32 offsets (reference tuple order, flattened)
#define O_ZQ   0
#define O_IDX  16777216
#define O_LOSS 16842752
#define O_PERP 16842753
#define O_CS   16842754
#define O_EMAW 16846850
#define O_W    17895426

// scratch inside d_out O_ZQ region (16,777,216 floats; dead until k_zq):
#define OFF_WSW   8388608      // swizzled w bf16: 256 grp x 8 chunk x 1024 B
#define OFF_CCNT  8912896      // 65536 ints
#define OFF_CIDS  8978432      // 65536 x 16 ints
#define OFF_OFFS  10027008     // 4097 ints
#define OFF_CUR   10031232     // 4096 ints
#define OFF_ROWS  10035328     // 65536 ints
#define OFF_GMIN  10100864     // 65536 uints
// zz -> EMAW region [0,65536); wwg -> EMAW [65536,69632)  (dead before k_dw)

typedef __attribute__((ext_vector_type(8))) short short8;   // 8 bf16
typedef __attribute__((ext_vector_type(4))) float f32x4;

__device__ __forceinline__ unsigned short f2bf(float f) {   // RNE
    unsigned u = __float_as_uint(f);
    return (unsigned short)((u + 0x7FFF + ((u >> 16) & 1)) >> 16);
}
__device__ __forceinline__ unsigned encf(float f) {         // order-preserving
    unsigned u = __float_as_uint(f);
    return (u >> 31) ? ~u : (u | 0x80000000u);
}
__device__ __forceinline__ float decf(unsigned e) {
    unsigned u = (e & 0x80000000u) ? (e & 0x7fffffffu) : ~e;
    return __uint_as_float(u);
}

// ---------------- z: fp32 -> bf16 row-layout + row sum-of-squares ----------
__global__ void k_prepz(const float* __restrict__ src, unsigned* __restrict__ dst,
                        float* __restrict__ ss) {
    int l   = threadIdx.x & 63;
    int row = blockIdx.x * 4 + (threadIdx.x >> 6);
    float4 v = ((const float4*)(src + (size_t)row * DIMD))[l];
    uint2 pk = make_uint2(f2bf(v.x) | (f2bf(v.y) << 16),
                          f2bf(v.z) | (f2bf(v.w) << 16));
    ((uint2*)dst)[(size_t)row * 64 + l] = pk;
    float s = v.x*v.x + v.y*v.y + v.z*v.z + v.w*v.w;
    #pragma unroll
    for (int off = 32; off; off >>= 1) s += __shfl_down(s, off);
    if (l == 0) ss[row] = s;
}

// ---------------- w: fp32 -> bf16 B-frag-swizzled + sum-of-squares ---------
// dest layout: group g (=k>>4), chunk c (=d>>5): 1 KB block, lane l=q*16+n16
// holds B[k=g*16+n16][kdim=c*32+q*8+j], 16 B per lane.
__global__ void k_prepw(const float* __restrict__ src, unsigned* __restrict__ dst,
                        float* __restrict__ ss) {
    int l   = threadIdx.x & 63;
    int row = blockIdx.x * 4 + (threadIdx.x >> 6);
    float4 v = ((const float4*)(src + (size_t)row * DIMD))[l];
    uint2 pk = make_uint2(f2bf(v.x) | (f2bf(v.y) << 16),
                          f2bf(v.z) | (f2bf(v.w) << 16));
    int g = row >> 4, n16 = row & 15;
    int c = l >> 3, q = (l >> 1) & 3, half = l & 1;
    ((uint2*)dst)[g * 1024 + c * 128 + (q * 16 + n16) * 2 + half] = pk;
    float s = v.x*v.x + v.y*v.y + v.z*v.z + v.w*v.w;
    #pragma unroll
    for (int off = 32; off; off >>= 1) s += __shfl_down(s, off);
    if (l == 0) ss[row] = s;
}

// ---------------- coarse sweep, pass 0: per-row bf16-core min --------------
// 512 blocks x 256 thr = 2048 independent waves. Wave W: rows rg=W>>1 (64 rows,
// 4 A-sets), K-half h=W&1 (128 groups of 16 codes). B-frags loaded DIRECT from
// global (1 KB coalesced per (group,chunk)); no LDS, no barriers.
__launch_bounds__(256, 2)
__global__ void k_pass0(const unsigned* __restrict__ zbf,
                        const uint4* __restrict__ wsw4,
                        const float* __restrict__ wwg,
                        unsigned* __restrict__ gmin) {
    const int t = threadIdx.x, wv = t >> 6, l = t & 63;
    const int q = l >> 4, n16 = l & 15;
    const int W = blockIdx.x * 4 + wv;
    const int row0 = (W >> 1) * 64;
    const int g0 = (W & 1) * 128;

    union U { uint4 u; short8 s; } afr[4][8];
    #pragma unroll
    for (int s = 0; s < 4; ++s) {
        const char* zb = (const char*)zbf + ((size_t)(row0 + s * 16 + n16) << 9) + q * 16;
        #pragma unroll
        for (int c = 0; c < 8; ++c) afr[s][c].u = *(const uint4*)(zb + c * 64);
    }
    float minv[16];
    #pragma unroll
    for (int i = 0; i < 16; ++i) minv[i] = 3.0e38f;

    for (int g = 0; g < 128; ++g) {
        const int gg = g0 + g;
        const uint4* wp = wsw4 + gg * 512 + l;
        f32x4 acc[4];
        #pragma unroll
        for (int s = 0; s < 4; ++s) acc[s] = (f32x4){0.f, 0.f, 0.f, 0.f};
        #pragma unroll
        for (int c = 0; c < 8; ++c) {
            U bf; bf.u = wp[c * 64];
            #pragma unroll
            for (int s = 0; s < 4; ++s)
                acc[s] = __builtin_amdgcn_mfma_f32_16x16x32_bf16(afr[s][c].s, bf.s, acc[s], 0, 0, 0);
        }
        float wwv = wwg[gg * 16 + n16];
        #pragma unroll
        for (int s = 0; s < 4; ++s)
            #pragma unroll
            for (int r = 0; r < 4; ++r)
                minv[s*4+r] = fminf(minv[s*4+r], fmaf(-2.f, acc[s][r], wwv));
    }
    #pragma unroll
    for (int i = 0; i < 16; ++i) {
        float m = minv[i];
        #pragma unroll
        for (int msk = 1; msk < 16; msk <<= 1) m = fminf(m, __shfl_xor(m, msk));
        if (n16 == 0)
            atomicMin(&gmin[row0 + (i >> 2) * 16 + q * 4 + (i & 3)], encf(m));
    }
}

// ---------------- coarse sweep, pass 1: emit margin candidates -------------
__launch_bounds__(256, 2)
__global__ void k_pass1(const unsigned* __restrict__ zbf,
                        const uint4* __restrict__ wsw4,
                        const float* __restrict__ wwg,
                        const unsigned* __restrict__ gmin,
                        int* __restrict__ ccnt,
                        int* __restrict__ cids) {
    const int t = threadIdx.x, wv = t >> 6, l = t & 63;
    const int q = l >> 4, n16 = l & 15;
    const int W = blockIdx.x * 4 + wv;
    const int row0 = (W >> 1) * 64;
    const int g0 = (W & 1) * 128;

    union U { uint4 u; short8 s; } afr[4][8];
    #pragma unroll
    for (int s = 0; s < 4; ++s) {
        const char* zb = (const char*)zbf + ((size_t)(row0 + s * 16 + n16) << 9) + q * 16;
        #pragma unroll
        for (int c = 0; c < 8; ++c) afr[s][c].u = *(const uint4*)(zb + c * 64);
    }
    float thr[16];
    #pragma unroll
    for (int i = 0; i < 16; ++i)
        thr[i] = decf(gmin[row0 + (i >> 2) * 16 + q * 4 + (i & 3)]) + MARGIN;

    for (int g = 0; g < 128; ++g) {
        const int gg = g0 + g;
        const uint4* wp = wsw4 + gg * 512 + l;
        f32x4 acc[4];
        #pragma unroll
        for (int s = 0; s < 4; ++s) acc[s] = (f32x4){0.f, 0.f, 0.f, 0.f};
        #pragma unroll
        for (int c = 0; c < 8; ++c) {
            U bf; bf.u = wp[c * 64];
            #pragma unroll
            for (int s = 0; s < 4; ++s)
                acc[s] = __builtin_amdgcn_mfma_f32_16x16x32_bf16(afr[s][c].s, bf.s, acc[s], 0, 0, 0);
        }
        float wwv = wwg[gg * 16 + n16];
        #pragma unroll
        for (int s = 0; s < 4; ++s)
            #pragma unroll
            for (int r = 0; r < 4; ++r) {
                float core = fmaf(-2.f, acc[s][r], wwv);
                if (core <= thr[s*4+r]) {
                    int row = row0 + s * 16 + q * 4 + r;
                    int pos = atomicAdd(&ccnt[row], 1);
                    if (pos < 16) cids[row * 16 + pos] = gg * 16 + n16;
                }
            }
    }
}

// ---------------- fp32 rescore of candidates ----------------
__global__ void k_refine(const float* __restrict__ z,
                         const float* __restrict__ w,
                         const float* __restrict__ zz,
                         const float* __restrict__ wwg,
                         const int* __restrict__ ccnt,
                         const int* __restrict__ cids,
                         float* __restrict__ counts,
                         int*   __restrict__ idxi,
                         float* __restrict__ idxf) {
    int l   = threadIdx.x & 63;
    int row = blockIdx.x * 4 + (threadIdx.x >> 6);
    int n = ccnt[row]; if (n > 16) n = 16;
    float4 zv = ((const float4*)(z + (size_t)row * DIMD))[l];
    float zzv = zz[row];
    float bd = 3.0e38f; int bi = 0x7fffffff;
    for (int j = 0; j < n; ++j) {
        int k = cids[row * 16 + j];
        float4 wv = ((const float4*)(w + (size_t)k * DIMD))[l];
        float s = zv.x*wv.x + zv.y*wv.y + zv.z*wv.z + zv.w*wv.w;
        #pragma unroll
        for (int off = 32; off; off >>= 1) s += __shfl_xor(s, off);
        float d = (zzv + wwg[k]) - 2.0f * s;
        if (d < bd || (d == bd && k < bi)) { bd = d; bi = k; }
    }
    if (l == 0) {
        idxi[row] = bi;
        idxf[row] = (float)bi;
        atomicAdd(&counts[bi], 1.0f);
    }
}

// ---------------- exclusive prefix sum of counts -> offs, cursor ----------
__global__ void k_offsets(const float* __restrict__ counts,
                          int* __restrict__ offs, int* __restrict__ cursor) {
    __shared__ int sc[1024];
    int t = threadIdx.x;
    int c[4]; int s = 0;
    #pragma unroll
    for (int i = 0; i < 4; ++i) { c[i] = (int)counts[t * 4 + i]; s += c[i]; }
    sc[t] = s;
    __syncthreads();
    for (int d = 1; d < 1024; d <<= 1) {
        int v = (t >= d) ? sc[t - d] : 0;
        __syncthreads();
        sc[t] += v;
        __syncthreads();
    }
    int o = sc[t] - s;
    #pragma unroll
    for (int i = 0; i < 4; ++i) { offs[t*4+i] = o; cursor[t*4+i] = o; o += c[i]; }
    if (t == 1023) offs[4096] = sc[1023];
}

// ---------------- fill inverted row lists ----------------
__global__ void k_fill(const int* __restrict__ idxi, int* __restrict__ cursor,
                       int* __restrict__ rows) {
    int r = blockIdx.x * 256 + threadIdx.x;
    int k = idxi[r];
    int pos = atomicAdd(&cursor[k], 1);
    rows[pos] = r;
}

// ---------------- dw[k,:] = sum of z rows assigned to k -------------------
// 256 thr: 4 row-slots x 64 d-lanes (4x parallel over the cluster).
__global__ void k_dw(const float* __restrict__ z, const int* __restrict__ offs,
                     const int* __restrict__ rows, float* __restrict__ dw) {
    __shared__ float4 part[4][64];
    int k = blockIdx.x;
    int l = threadIdx.x & 63, j = threadIdx.x >> 6;
    int o0 = offs[k], o1 = offs[k + 1];
    float4 a = make_float4(0.f, 0.f, 0.f, 0.f);
    for (int i = o0 + j; i < o1; i += 4) {
        int r = rows[i];
        float4 v = ((const float4*)(z + (size_t)r * DIMD))[l];
        a.x += v.x; a.y += v.y; a.z += v.z; a.w += v.w;
    }
    part[j][l] = a;
    __syncthreads();
    if (j == 0) {
        float4 b = part[0][l], c = part[1][l], d = part[2][l], e = part[3][l];
        a = make_float4(b.x+c.x+d.x+e.x, b.y+c.y+d.y+e.y,
                        b.z+c.z+d.z+e.z, b.w+c.w+d.w+e.w);
        ((float4*)(dw + (size_t)k * DIMD))[l] = a;
    }
}

// ---------------- cluster-size EMA + perplexity ----------------
__global__ void k_cs(const float* __restrict__ ema_cs,
                     float* __restrict__ cs_io,
                     float* __restrict__ perp) {
    __shared__ float2 red[16];
    int t = threadIdx.x;
    float csd[4];
    float nl = 0.f, el = 0.f;
    #pragma unroll
    for (int i = 0; i < 4; ++i) {
        int k = t * 4 + i;
        float c  = cs_io[k];
        float cd = ema_cs[k] * 0.99f + 0.01f * c;
        csd[i] = cd;
        nl += cd;
        float p = c * (1.0f / 65536.0f);
        el += p * logf(p + 1e-10f);
    }
    #pragma unroll
    for (int off = 32; off; off >>= 1) { nl += __shfl_down(nl, off); el += __shfl_down(el, off); }
    if ((t & 63) == 0) red[t >> 6] = make_float2(nl, el);
    __syncthreads();
    if (t == 0) {
        float n = 0.f, e = 0.f;
        for (int i = 0; i < 16; ++i) { n += red[i].x; e += red[i].y; }
        red[0] = make_float2(n, e);
        perp[0] = expf(-e);
    }
    __syncthreads();
    float n = red[0].x;
    float scale = n / (n + 4096.0f * 1e-5f);
    #pragma unroll
    for (int i = 0; i < 4; ++i)
        cs_io[t * 4 + i] = (csd[i] + 1e-5f) * scale;
}

// ---------------- new_ema_w (in-place over dw) + new_weight ----------------
__global__ void k_emaw(const float* __restrict__ ema_w,
                       const float* __restrict__ cs,
                       float* __restrict__ emaw_io,
                       float* __restrict__ wout) {
    int i = (blockIdx.x * 256 + threadIdx.x) * 4;
    int k = i >> 8;
    float4 dv = *(const float4*)(emaw_io + i);
    float4 ev = *(const float4*)(ema_w + i);
    float c = cs[k];
    float4 ne;
    ne.x = ev.x * 0.99f + 0.01f * dv.x;
    ne.y = ev.y * 0.99f + 0.01f * dv.y;
    ne.z = ev.z * 0.99f + 0.01f * dv.z;
    ne.w = ev.w * 0.99f + 0.01f * dv.w;
    *(float4*)(emaw_io + i) = ne;
    float4 nw = make_float4(ne.x / c, ne.y / c, ne.z / c, ne.w / c);
    *(float4*)(wout + i) = nw;
}

// ---------------- z_q gather + straight-through + loss partial -------------
__global__ void k_zq(const float* __restrict__ z,
                     const float* __restrict__ wnew,
                     const int* __restrict__ idxi,
                     float* __restrict__ zq,
                     float* __restrict__ sqacc) {   // 256 accumulators
    __shared__ float red[4];
    int i = (blockIdx.x * 256 + threadIdx.x) * 4;
    int n = i >> 8;
    int d = i & 255;
    int k = idxi[n];
    float4 wv = *(const float4*)(wnew + (k << 8) + d);
    float4 zv = *(const float4*)(z + i);
    float4 o;
    o.x = zv.x + (wv.x - zv.x);
    o.y = zv.y + (wv.y - zv.y);
    o.z = zv.z + (wv.z - zv.z);
    o.w = zv.w + (wv.w - zv.w);
    *(float4*)(zq + i) = o;
    float dx = wv.x - zv.x, dy = wv.y - zv.y, dz = wv.z - zv.z, dw_ = wv.w - zv.w;
    float s = dx*dx + dy*dy + dz*dz + dw_*dw_;
    #pragma unroll
    for (int off = 32; off; off >>= 1) s += __shfl_down(s, off);
    int lane = threadIdx.x & 63;
    if (lane == 0) red[threadIdx.x >> 6] = s;
    __syncthreads();
    if (threadIdx.x == 0)
        atomicAdd(&sqacc[blockIdx.x & 255], red[0] + red[1] + red[2] + red[3]);
}

__global__ void k_final(const float* __restrict__ sqacc, float* __restrict__ loss) {
    __shared__ float red[4];
    int t = threadIdx.x;
    float s = sqacc[t];
    #pragma unroll
    for (int off = 32; off; off >>= 1) s += __shfl_down(s, off);
    if ((t & 63) == 0) red[t >> 6] = s;
    __syncthreads();
    if (t == 0)
        loss[0] = 1.25f * (red[0] + red[1] + red[2] + red[3]) * (1.0f / 16777216.0f);
}

extern "C" void kernel_launch(void* const* d_in, const int* in_sizes, int n_in,
                              void* d_out, int out_size, void* d_ws, size_t ws_size,
                              hipStream_t stream) {
    const float* z      = (const float*)d_in[0];
    const float* weight = (const float*)d_in[1];
    const float* ema_w  = (const float*)d_in[2];
    const float* ema_cs = (const float*)d_in[3];
    float* out = (float*)d_out;
    float* ws  = (float*)d_ws;

    float* scal = ws + 4096;             // 256 floats
    int*   idxi = (int*)(ws + 8192);     // 65536 ints

    unsigned* zbf    = (unsigned*)(out + O_ZQ);
    uint4*    wsw4   = (uint4*)(out + O_ZQ + OFF_WSW);
    int*      ccnt   = (int*)(out + O_ZQ + OFF_CCNT);
    int*      cids   = (int*)(out + O_ZQ + OFF_CIDS);
    int*      offs   = (int*)(out + O_ZQ + OFF_OFFS);
    int*      cursor = (int*)(out + O_ZQ + OFF_CUR);
    int*      rows   = (int*)(out + O_ZQ + OFF_ROWS);
    unsigned* gmin   = (unsigned*)(out + O_ZQ + OFF_GMIN);
    float*    zz     = out + O_EMAW;           // dead before k_dw writes dw
    float*    wwg    = out + O_EMAW + 65536;

    hipMemsetAsync(scal,       0,    256 * 4, stream);
    hipMemsetAsync(out + O_CS, 0,    (size_t)KCB * 4, stream);
    hipMemsetAsync(ccnt,       0,    (size_t)NPTS * 4, stream);
    hipMemsetAsync(gmin,       0xFF, (size_t)NPTS * 4, stream);

    k_prepz  <<<NPTS / 4, 256, 0, stream>>>(z, zbf, zz);
    k_prepw  <<<KCB  / 4, 256, 0, stream>>>(weight, (unsigned*)wsw4, wwg);
    k_pass0  <<<512, 256, 0, stream>>>(zbf, wsw4, wwg, gmin);
    k_pass1  <<<512, 256, 0, stream>>>(zbf, wsw4, wwg, gmin, ccnt, cids);
    k_refine <<<NPTS / 4, 256, 0, stream>>>(z, weight, zz, wwg, ccnt, cids,
                                            out + O_CS, idxi, out + O_IDX);
    k_offsets<<<1, 1024, 0, stream>>>(out + O_CS, offs, cursor);
    k_fill   <<<NPTS / 256, 256, 0, stream>>>(idxi, cursor, rows);
    k_cs     <<<1, 1024, 0, stream>>>(ema_cs, out + O_CS, out + O_PERP);
    k_dw     <<<KCB, 256, 0, stream>>>(z, offs, rows, out + O_EMAW);
    k_emaw   <<<(KCB * DIMD) / 1024, 256, 0, stream>>>(ema_w, out + O_CS,
                                                       out + O_EMAW, out + O_W);
    k_zq     <<<(NPTS * DIMD) / 1024, 256, 0, stream>>>(z, out + O_W, idxi,
                                                        out + O_ZQ, scal);
    k_final  <<<1, 256, 0, stream>>>(scal, out + O_LOSS);
}